// Round 1
// baseline (69.745 us; speedup 1.0000x reference)
//
#include <hip/hip_runtime.h>
#include <math.h>

#define D_MODEL 128
#define D_STATE 64
#define VOCAB 2000
#define SEQ_L 4096
#define BATCH 32
#define JSPLIT 32
#define CHUNK (SEQ_L / JSPLIT)   // 128
#define LN_EPS 1e-5f

// ---------------- Kernel 1: layernorm the embedding table ----------------
// e_ln[v,m] = LN(emb[v,:])[m] * ln_w[m] + ln_b[m]
__global__ __launch_bounds__(64) void ln_embed_kernel(
    const float* __restrict__ emb, const float* __restrict__ ln_w,
    const float* __restrict__ ln_b, float* __restrict__ e_ln) {
  int v = blockIdx.x;
  int t = threadIdx.x;  // 0..63
  const float* row = emb + v * D_MODEL;
  float h0 = row[t];
  float h1 = row[t + 64];
  float s = h0 + h1;
#pragma unroll
  for (int off = 32; off; off >>= 1) s += __shfl_xor(s, off);
  float mu = s * (1.0f / D_MODEL);
  float d0 = h0 - mu, d1 = h1 - mu;
  float q = d0 * d0 + d1 * d1;
#pragma unroll
  for (int off = 32; off; off >>= 1) q += __shfl_xor(q, off);
  float var = q * (1.0f / D_MODEL);
  float rs = rsqrtf(var + LN_EPS);
  e_ln[v * D_MODEL + t]      = d0 * rs * ln_w[t]      + ln_b[t];
  e_ln[v * D_MODEL + t + 64] = d1 * rs * ln_w[t + 64] + ln_b[t + 64];
}

// ---------------- Kernel 2: closed-form pooled conv weights ----------------
// Wv[j,m] = cumK[m, L-1-j] + D[m],
// cumK[m,r] = sum_n C[m,n] * (1 - lam^{r+1})/(1 - lam),  lam = exp(dt_m * A_n)
//           = sum_n C[m,n] * expm1(x*(r+1)) / expm1(x),  x = dt_m * A_n (< 0)
__global__ __launch_bounds__(256) void weights_kernel(
    const float* __restrict__ A_log, const float* __restrict__ Dp,
    const float* __restrict__ C_re, const float* __restrict__ log_dt,
    float* __restrict__ Wv) {
  __shared__ float Ash[D_STATE];
  int tid = threadIdx.x;
  if (tid < D_STATE) Ash[tid] = -expf(A_log[tid]);
  __syncthreads();
  int gid = blockIdx.x * 256 + tid;
  int m = gid & (D_MODEL - 1);
  int j = gid >> 7;           // 0..4095
  float r1 = (float)(SEQ_L - j);  // r+1 where r = L-1-j
  float dt = expf(log_dt[m]);
  float s = 0.0f;
#pragma unroll 8
  for (int n = 0; n < D_STATE; ++n) {
    float x = dt * Ash[n];                 // negative
    float num = expm1f(x * r1);
    float den = expm1f(x);
    s += C_re[m * D_STATE + n] * (num / den);
  }
  Wv[j * D_MODEL + m] = s + Dp[m];
}

// ---------------- Kernel 3: gather-weighted reduction ----------------
// part[b,s,m] = sum_{j in chunk s} e_ln[x[b,j], m] * Wv[j, m]   (f64 accum)
__global__ __launch_bounds__(128) void reduce_kernel(
    const int* __restrict__ x, const float* __restrict__ e_ln,
    const float* __restrict__ Wv, float* __restrict__ part) {
  int b = blockIdx.x;
  int sIdx = blockIdx.y;
  int m = threadIdx.x;
  const int* xrow = x + b * SEQ_L + sIdx * CHUNK;
  const float* wbase = Wv + sIdx * CHUNK * D_MODEL + m;
  double acc = 0.0;
#pragma unroll 4
  for (int j = 0; j < CHUNK; ++j) {
    int tok = xrow[j];
    float ev = e_ln[tok * D_MODEL + m];
    float wv = wbase[j * D_MODEL];
    acc = fma((double)ev, (double)wv, acc);
  }
  part[(b * JSPLIT + sIdx) * D_MODEL + m] = (float)acc;
}

// ---------------- Kernel 4: finalize: pool + classifier ----------------
__global__ __launch_bounds__(64) void final_kernel(
    const float* __restrict__ part, const float* __restrict__ W_cls,
    const float* __restrict__ b_cls, float* __restrict__ out) {
  int b = blockIdx.x;
  int t = threadIdx.x;  // 0..63
  float p1 = 0.0f, p2 = 0.0f;
  for (int s = 0; s < JSPLIT; ++s) {
    p1 += part[(b * JSPLIT + s) * D_MODEL + t];
    p2 += part[(b * JSPLIT + s) * D_MODEL + t + 64];
  }
  p1 *= (1.0f / SEQ_L);
  p2 *= (1.0f / SEQ_L);
  float c0 = p1 * W_cls[t]           + p2 * W_cls[t + 64];
  float c1 = p1 * W_cls[D_MODEL + t] + p2 * W_cls[D_MODEL + t + 64];
#pragma unroll
  for (int off = 32; off; off >>= 1) {
    c0 += __shfl_xor(c0, off);
    c1 += __shfl_xor(c1, off);
  }
  if (t == 0) {
    out[b * 2 + 0] = c0 + b_cls[0];
    out[b * 2 + 1] = c1 + b_cls[1];
  }
}

extern "C" void kernel_launch(void* const* d_in, const int* in_sizes, int n_in,
                              void* d_out, int out_size, void* d_ws, size_t ws_size,
                              hipStream_t stream) {
  const int*   x      = (const int*)d_in[0];
  const float* emb    = (const float*)d_in[1];
  const float* ln_w   = (const float*)d_in[2];
  const float* ln_b   = (const float*)d_in[3];
  const float* A_log  = (const float*)d_in[4];
  const float* Dp     = (const float*)d_in[5];
  const float* C_re   = (const float*)d_in[6];
  const float* log_dt = (const float*)d_in[7];
  const float* W_cls  = (const float*)d_in[8];
  const float* b_cls  = (const float*)d_in[9];
  float* out = (float*)d_out;

  char* ws = (char*)d_ws;
  float* e_ln = (float*)(ws);                        // 2000*128*4   = 1,024,000 B
  float* Wv   = (float*)(ws + 1048576);              // 4096*128*4   = 2,097,152 B
  float* part = (float*)(ws + 1048576 + 2097152);    // 32*32*128*4  =   524,288 B

  ln_embed_kernel<<<VOCAB, 64, 0, stream>>>(emb, ln_w, ln_b, e_ln);
  weights_kernel<<<(SEQ_L * D_MODEL) / 256, 256, 0, stream>>>(A_log, Dp, C_re, log_dt, Wv);
  reduce_kernel<<<dim3(BATCH, JSPLIT), 128, 0, stream>>>(x, e_ln, Wv, part);
  final_kernel<<<BATCH, 64, 0, stream>>>(part, W_cls, b_cls, out);
}

// Round 2
// 44.212 us; speedup vs baseline: 1.5775x; 1.5775x over previous
//
#include <hip/hip_runtime.h>
#include <math.h>

#define D_MODEL 128
#define D_STATE 64
#define VOCAB 2000
#define SEQ_L 4096
#define BATCH 32
#define JSPLIT 32
#define CHUNK (SEQ_L / JSPLIT)   // 128
#define SEG 16                   // j's per weights-thread
#define LN_EPS 1e-5f

// ---------------- Kernel 1: layernorm the embedding table ----------------
__global__ __launch_bounds__(64) void ln_embed_kernel(
    const float* __restrict__ emb, const float* __restrict__ ln_w,
    const float* __restrict__ ln_b, float* __restrict__ e_ln) {
  int v = blockIdx.x;
  int t = threadIdx.x;  // 0..63
  const float* row = emb + v * D_MODEL;
  float h0 = row[t];
  float h1 = row[t + 64];
  float s = h0 + h1;
#pragma unroll
  for (int off = 32; off; off >>= 1) s += __shfl_xor(s, off);
  float mu = s * (1.0f / D_MODEL);
  float d0 = h0 - mu, d1 = h1 - mu;
  float q = d0 * d0 + d1 * d1;
#pragma unroll
  for (int off = 32; off; off >>= 1) q += __shfl_xor(q, off);
  float var = q * (1.0f / D_MODEL);
  float rs = rsqrtf(var + LN_EPS);
  e_ln[v * D_MODEL + t]      = d0 * rs * ln_w[t]      + ln_b[t];
  e_ln[v * D_MODEL + t + 64] = d1 * rs * ln_w[t + 64] + ln_b[t + 64];
}

// ---------------- Kernel 2a: per-(m,n) parameter tables ----------------
// x[n][m] = dt_m * A_n (<0), q = exp(x), ratio = C[m,n] * 1/(1-q) = -C/expm1(x)
__global__ __launch_bounds__(256) void params_kernel(
    const float* __restrict__ A_log, const float* __restrict__ C_re,
    const float* __restrict__ log_dt, float* __restrict__ xs,
    float* __restrict__ qs, float* __restrict__ rs) {
  int tid = blockIdx.x * 256 + threadIdx.x;  // 0..8191, tid = n*128 + m
  int m = tid & (D_MODEL - 1);
  int n = tid >> 7;
  float dt = expf(log_dt[m]);
  float A = -expf(A_log[n]);
  float x = dt * A;                          // negative
  xs[tid] = x;
  qs[tid] = expf(x);
  rs[tid] = C_re[m * D_STATE + n] * (-1.0f / expm1f(x));
}

// ---------------- Kernel 2b: pooled conv weights via geometric recurrence ----
// Wv[j,m] = D_m + sum_n ratio_{mn} * (1 - q_{mn}^{L-j})
//         = base_m - sum_n ratio_{mn} * q^{L-j}
// Per thread: one m, SEG consecutive j. Seed g = q^{r1_end} with one expf,
// then g *= q walking j downward (r1 upward, g decays -> safe).
__global__ __launch_bounds__(128) void weights_kernel(
    const float* __restrict__ xs, const float* __restrict__ qs,
    const float* __restrict__ rs, const float* __restrict__ Dp,
    float* __restrict__ Wv) {
  int m = threadIdx.x;             // 0..127
  int j0 = blockIdx.x * SEG;
  float acc[SEG];
#pragma unroll
  for (int k = 0; k < SEG; ++k) acc[k] = 0.0f;
  float bs = 0.0f;
  float r1_end = (float)(SEQ_L - j0 - (SEG - 1));  // smallest exponent in seg
  for (int n = 0; n < D_STATE; ++n) {
    float x = xs[n * D_MODEL + m];
    float q = qs[n * D_MODEL + m];
    float r = rs[n * D_MODEL + m];
    bs += r;
    float g = expf(x * r1_end);    // q^{L - j0 - (SEG-1)}
    acc[SEG - 1] += r * g;
#pragma unroll
    for (int jj = SEG - 2; jj >= 0; --jj) {
      g *= q;                      // exponent +1 as j decreases
      acc[jj] += r * g;
    }
  }
  float base = Dp[m] + bs;
#pragma unroll
  for (int k = 0; k < SEG; ++k)
    Wv[(j0 + k) * D_MODEL + m] = base - acc[k];
}

// ---------------- Kernel 3: gather-weighted reduction ----------------
__global__ __launch_bounds__(128) void reduce_kernel(
    const int* __restrict__ x, const float* __restrict__ e_ln,
    const float* __restrict__ Wv, float* __restrict__ part) {
  int b = blockIdx.x;
  int sIdx = blockIdx.y;
  int m = threadIdx.x;
  const int* xrow = x + b * SEQ_L + sIdx * CHUNK;
  const float* wbase = Wv + sIdx * CHUNK * D_MODEL + m;
  double acc0 = 0.0, acc1 = 0.0;
#pragma unroll 2
  for (int j = 0; j < CHUNK; j += 2) {
    int tok0 = xrow[j];
    int tok1 = xrow[j + 1];
    float ev0 = e_ln[tok0 * D_MODEL + m];
    float wv0 = wbase[j * D_MODEL];
    float ev1 = e_ln[tok1 * D_MODEL + m];
    float wv1 = wbase[(j + 1) * D_MODEL];
    acc0 = fma((double)ev0, (double)wv0, acc0);
    acc1 = fma((double)ev1, (double)wv1, acc1);
  }
  part[(b * JSPLIT + sIdx) * D_MODEL + m] = (float)(acc0 + acc1);
}

// ---------------- Kernel 4: finalize: pool + classifier ----------------
__global__ __launch_bounds__(64) void final_kernel(
    const float* __restrict__ part, const float* __restrict__ W_cls,
    const float* __restrict__ b_cls, float* __restrict__ out) {
  int b = blockIdx.x;
  int t = threadIdx.x;  // 0..63
  float p1 = 0.0f, p2 = 0.0f;
  for (int s = 0; s < JSPLIT; ++s) {
    p1 += part[(b * JSPLIT + s) * D_MODEL + t];
    p2 += part[(b * JSPLIT + s) * D_MODEL + t + 64];
  }
  p1 *= (1.0f / SEQ_L);
  p2 *= (1.0f / SEQ_L);
  float c0 = p1 * W_cls[t]           + p2 * W_cls[t + 64];
  float c1 = p1 * W_cls[D_MODEL + t] + p2 * W_cls[D_MODEL + t + 64];
#pragma unroll
  for (int off = 32; off; off >>= 1) {
    c0 += __shfl_xor(c0, off);
    c1 += __shfl_xor(c1, off);
  }
  if (t == 0) {
    out[b * 2 + 0] = c0 + b_cls[0];
    out[b * 2 + 1] = c1 + b_cls[1];
  }
}

extern "C" void kernel_launch(void* const* d_in, const int* in_sizes, int n_in,
                              void* d_out, int out_size, void* d_ws, size_t ws_size,
                              hipStream_t stream) {
  const int*   x      = (const int*)d_in[0];
  const float* emb    = (const float*)d_in[1];
  const float* ln_w   = (const float*)d_in[2];
  const float* ln_b   = (const float*)d_in[3];
  const float* A_log  = (const float*)d_in[4];
  const float* Dp     = (const float*)d_in[5];
  const float* C_re   = (const float*)d_in[6];
  const float* log_dt = (const float*)d_in[7];
  const float* W_cls  = (const float*)d_in[8];
  const float* b_cls  = (const float*)d_in[9];
  float* out = (float*)d_out;

  char* ws = (char*)d_ws;
  float* e_ln = (float*)(ws);                        // 2000*128*4   = 1,024,000 B
  float* Wv   = (float*)(ws + 1048576);              // 4096*128*4   = 2,097,152 B
  float* part = (float*)(ws + 1048576 + 2097152);    // 32*32*128*4  =   524,288 B
  // params tables alias the `part` region: disjoint liveness
  // (params live for kernels 2a/2b; part live for kernels 3/4)
  float* xs = part;                                  // 8192*4 = 32 KB
  float* qs = part + 8192;                           // 32 KB
  float* rs = part + 16384;                          // 32 KB

  ln_embed_kernel<<<VOCAB, 64, 0, stream>>>(emb, ln_w, ln_b, e_ln);
  params_kernel<<<32, 256, 0, stream>>>(A_log, C_re, log_dt, xs, qs, rs);
  weights_kernel<<<SEQ_L / SEG, 128, 0, stream>>>(xs, qs, rs, Dp, Wv);
  reduce_kernel<<<dim3(BATCH, JSPLIT), 128, 0, stream>>>(x, e_ln, Wv, part);
  final_kernel<<<BATCH, 64, 0, stream>>>(part, W_cls, b_cls, out);
}

// Round 3
// 39.497 us; speedup vs baseline: 1.7658x; 1.1194x over previous
//
#include <hip/hip_runtime.h>
#include <math.h>

#define D_MODEL 128
#define D_STATE 64
#define VOCAB 2000
#define SEQ_L 4096
#define BATCH 32
#define JSPLIT 64
#define CHUNK (SEQ_L / JSPLIT)   // 64
#define SEG 16                   // j's per weights-thread
#define LN_EPS 1e-5f

// ---------------- Kernel 1: layernorm the embedding table ----------------
// 4 vocab rows per block (256 threads = 4 waves, one row per wave)
__global__ __launch_bounds__(256) void ln_embed_kernel(
    const float* __restrict__ emb, const float* __restrict__ ln_w,
    const float* __restrict__ ln_b, float* __restrict__ e_ln) {
  int v = blockIdx.x * 4 + (threadIdx.x >> 6);
  int t = threadIdx.x & 63;
  const float* row = emb + v * D_MODEL;
  float h0 = row[t];
  float h1 = row[t + 64];
  float s = h0 + h1;
#pragma unroll
  for (int off = 32; off; off >>= 1) s += __shfl_xor(s, off);
  float mu = s * (1.0f / D_MODEL);
  float d0 = h0 - mu, d1 = h1 - mu;
  float q = d0 * d0 + d1 * d1;
#pragma unroll
  for (int off = 32; off; off >>= 1) q += __shfl_xor(q, off);
  float var = q * (1.0f / D_MODEL);
  float rs = rsqrtf(var + LN_EPS);
  e_ln[v * D_MODEL + t]      = d0 * rs * ln_w[t]      + ln_b[t];
  e_ln[v * D_MODEL + t + 64] = d1 * rs * ln_w[t + 64] + ln_b[t + 64];
}

// ---------------- Kernel 2a: per-(m,n) parameter tables ----------------
__global__ __launch_bounds__(256) void params_kernel(
    const float* __restrict__ A_log, const float* __restrict__ C_re,
    const float* __restrict__ log_dt, float* __restrict__ xs,
    float* __restrict__ qs, float* __restrict__ rs) {
  int tid = blockIdx.x * 256 + threadIdx.x;  // tid = n*128 + m
  int m = tid & (D_MODEL - 1);
  int n = tid >> 7;
  float dt = expf(log_dt[m]);
  float A = -expf(A_log[n]);
  float x = dt * A;                          // negative
  xs[tid] = x;
  qs[tid] = expf(x);
  rs[tid] = C_re[m * D_STATE + n] * (-1.0f / expm1f(x));
}

// ---------------- Kernel 2b: pooled conv weights via geometric recurrence ----
// Wv[j,m] = D_m + sum_n ratio_{mn} * (1 - q_{mn}^{L-j})
__global__ __launch_bounds__(128) void weights_kernel(
    const float* __restrict__ xs, const float* __restrict__ qs,
    const float* __restrict__ rs, const float* __restrict__ Dp,
    float* __restrict__ Wv) {
  int m = threadIdx.x;             // 0..127
  int j0 = blockIdx.x * SEG;
  float acc[SEG];
#pragma unroll
  for (int k = 0; k < SEG; ++k) acc[k] = 0.0f;
  float bs = 0.0f;
  float r1_end = (float)(SEQ_L - j0 - (SEG - 1));  // smallest exponent in seg
  for (int n = 0; n < D_STATE; ++n) {
    float x = xs[n * D_MODEL + m];
    float q = qs[n * D_MODEL + m];
    float r = rs[n * D_MODEL + m];
    bs += r;
    float g = expf(x * r1_end);    // q^{L - j0 - (SEG-1)}
    acc[SEG - 1] += r * g;
#pragma unroll
    for (int jj = SEG - 2; jj >= 0; --jj) {
      g *= q;
      acc[jj] += r * g;
    }
  }
  float base = Dp[m] + bs;
#pragma unroll
  for (int k = 0; k < SEG; ++k)
    Wv[(j0 + k) * D_MODEL + m] = base - acc[k];
}

// ---------------- Kernel 3: gather-weighted reduction ----------------
// part[b,s,m] = sum_{j in chunk s} e_ln[x[b,j], m] * Wv[j, m]
// Tokens staged in LDS first -> gather loop has no global->global dependency.
__global__ __launch_bounds__(128) void reduce_kernel(
    const int* __restrict__ x, const float* __restrict__ e_ln,
    const float* __restrict__ Wv, float* __restrict__ part) {
  __shared__ int toks[CHUNK];
  int b = blockIdx.x;
  int sIdx = blockIdx.y;
  int m = threadIdx.x;
  if (threadIdx.x < CHUNK)
    toks[threadIdx.x] = x[b * SEQ_L + sIdx * CHUNK + threadIdx.x];
  __syncthreads();
  const float* wbase = Wv + sIdx * CHUNK * D_MODEL + m;
  float a0 = 0.0f, a1 = 0.0f, a2 = 0.0f, a3 = 0.0f;
#pragma unroll
  for (int j = 0; j < CHUNK; j += 4) {
    int t0 = toks[j], t1 = toks[j + 1], t2 = toks[j + 2], t3 = toks[j + 3];
    float e0 = e_ln[t0 * D_MODEL + m];
    float e1 = e_ln[t1 * D_MODEL + m];
    float e2 = e_ln[t2 * D_MODEL + m];
    float e3 = e_ln[t3 * D_MODEL + m];
    float w0 = wbase[(j + 0) * D_MODEL];
    float w1 = wbase[(j + 1) * D_MODEL];
    float w2 = wbase[(j + 2) * D_MODEL];
    float w3 = wbase[(j + 3) * D_MODEL];
    a0 = fmaf(e0, w0, a0);
    a1 = fmaf(e1, w1, a1);
    a2 = fmaf(e2, w2, a2);
    a3 = fmaf(e3, w3, a3);
  }
  part[(b * JSPLIT + sIdx) * D_MODEL + m] = (a0 + a1) + (a2 + a3);
}

// ---------------- Kernel 4: finalize: pool + classifier ----------------
__global__ __launch_bounds__(64) void final_kernel(
    const float* __restrict__ part, const float* __restrict__ W_cls,
    const float* __restrict__ b_cls, float* __restrict__ out) {
  int b = blockIdx.x;
  int t = threadIdx.x;  // 0..63
  float p1 = 0.0f, p2 = 0.0f;
#pragma unroll 4
  for (int s = 0; s < JSPLIT; ++s) {
    p1 += part[(b * JSPLIT + s) * D_MODEL + t];
    p2 += part[(b * JSPLIT + s) * D_MODEL + t + 64];
  }
  p1 *= (1.0f / SEQ_L);
  p2 *= (1.0f / SEQ_L);
  float c0 = p1 * W_cls[t]           + p2 * W_cls[t + 64];
  float c1 = p1 * W_cls[D_MODEL + t] + p2 * W_cls[D_MODEL + t + 64];
#pragma unroll
  for (int off = 32; off; off >>= 1) {
    c0 += __shfl_xor(c0, off);
    c1 += __shfl_xor(c1, off);
  }
  if (t == 0) {
    out[b * 2 + 0] = c0 + b_cls[0];
    out[b * 2 + 1] = c1 + b_cls[1];
  }
}

extern "C" void kernel_launch(void* const* d_in, const int* in_sizes, int n_in,
                              void* d_out, int out_size, void* d_ws, size_t ws_size,
                              hipStream_t stream) {
  const int*   x      = (const int*)d_in[0];
  const float* emb    = (const float*)d_in[1];
  const float* ln_w   = (const float*)d_in[2];
  const float* ln_b   = (const float*)d_in[3];
  const float* A_log  = (const float*)d_in[4];
  const float* Dp     = (const float*)d_in[5];
  const float* C_re   = (const float*)d_in[6];
  const float* log_dt = (const float*)d_in[7];
  const float* W_cls  = (const float*)d_in[8];
  const float* b_cls  = (const float*)d_in[9];
  float* out = (float*)d_out;

  char* ws = (char*)d_ws;
  float* e_ln = (float*)(ws);                        // 2000*128*4   = 1,024,000 B
  float* Wv   = (float*)(ws + 1048576);              // 4096*128*4   = 2,097,152 B
  float* part = (float*)(ws + 1048576 + 2097152);    // 32*64*128*4  = 1,048,576 B
  // params tables alias `part`: disjoint liveness (params for 2a/2b, part for 3/4)
  float* xs = part;                                  // 32 KB
  float* qs = part + 8192;                           // 32 KB
  float* rs = part + 16384;                          // 32 KB

  ln_embed_kernel<<<VOCAB / 4, 256, 0, stream>>>(emb, ln_w, ln_b, e_ln);
  params_kernel<<<32, 256, 0, stream>>>(A_log, C_re, log_dt, xs, qs, rs);
  weights_kernel<<<SEQ_L / SEG, 128, 0, stream>>>(xs, qs, rs, Dp, Wv);
  reduce_kernel<<<dim3(BATCH, JSPLIT), 128, 0, stream>>>(x, e_ln, Wv, part);
  final_kernel<<<BATCH, 64, 0, stream>>>(part, W_cls, b_cls, out);
}